// Round 22
// baseline (564.381 us; speedup 1.0000x reference)
//
#include <hip/hip_runtime.h>

#define NN 20000
#define EE 320000
#define WTOT 27648
#define P3N (EE*64/8 + NN*128/8)

typedef unsigned short u16;
typedef unsigned int u32;
typedef __attribute__((ext_vector_type(8))) short bf16x8;
typedef __attribute__((ext_vector_type(8))) _Float16 f16x8;
typedef __attribute__((ext_vector_type(4))) float f32x4;

__device__ __forceinline__ float bf2f(u16 u){
  union { u32 i; float f; } v; v.i = ((u32)u) << 16; return v.f;
}
__device__ __forceinline__ u16 f2bf(float f){
  union { float f; u32 i; } v; v.f = f;
  u32 i = v.i;
  return (u16)((i + 0x7FFFu + ((i >> 16) & 1u)) >> 16);
}
__device__ __forceinline__ u16 f2h(float f){
  union { _Float16 h[2]; u32 u; } v; v.h[0] = (_Float16)f;
  return (u16)(v.u & 0xFFFF);
}
__device__ __forceinline__ float h2f(u16 u){
  union { u32 i; _Float16 h[2]; } v; v.i = u; return (float)v.h[0];
}
__device__ __forceinline__ u32 packh2(float a, float b){
  return ((u32)f2h(b) << 16) | (u32)f2h(a);
}
__device__ __forceinline__ float fsilu(float y){
  return y * __builtin_amdgcn_rcpf(1.f + __expf(-y));
}

// ---- merged prep: fp16 planes + counts zero + weight transposes ------------
__global__ __launch_bounds__(256) void k_prep_all(
    const float* __restrict__ elen, const float* __restrict__ node_in,
    u16* __restrict__ elen16, u16* __restrict__ node16,
    int* __restrict__ counts,
    const float* __restrict__ plw, const float* __restrict__ lew,
    const float* __restrict__ lw,
    u16* __restrict__ Bt1, u16* __restrict__ Bt2, u16* __restrict__ Bt3,
    const float* __restrict__ aw1, const float* __restrict__ aw2, const float* __restrict__ aw3,
    const float* __restrict__ rw1, const float* __restrict__ rw2,
    const float* __restrict__ sw1, const float* __restrict__ sw2, const float* __restrict__ sw3,
    u16* __restrict__ W)
{
  size_t gi = (size_t)blockIdx.x * 256 + threadIdx.x;
  if (gi < (size_t)P3N) {                      // fp32 -> fp16 planes (8/thread)
    const size_t n1 = (size_t)EE * 64 / 8;
    const float* src;
    u16* dst;
    if (gi < n1) { src = elen + gi*8; dst = elen16 + gi*8; }
    else { size_t j = gi - n1; src = node_in + j*8; dst = node16 + j*8; }
    float4 a = ((const float4*)src)[0];
    float4 b = ((const float4*)src)[1];
    uint4 vh;
    vh.x = packh2(a.x, a.y); vh.y = packh2(a.z, a.w);
    vh.z = packh2(b.x, b.y); vh.w = packh2(b.z, b.w);
    *(uint4*)dst = vh;
    return;
  }
  long j = (long)gi - P3N;
  if (j < NN) { counts[j] = 0; return; }
  j -= NN;
  if (j < 128*320) {                           // Bt1[n][k] = pre_lin_w[k][n]
    int n = (int)j / 320, k = (int)j % 320;
    Bt1[j] = f2h(plw[k*128 + n]);
    return;
  }
  j -= 128*320;
  if (j < 256*128) {                           // Bt2[h*64+c][k]
    int n = (int)j / 128, k = (int)j % 128;
    int h = n >> 6, c = n & 63;
    Bt2[j] = f2h(lew[(h*128 + k)*64 + c]);
    return;
  }
  j -= 256*128;
  if (j < 128*512) {                           // Bt3[n][k] = lin_w[k][n]
    int n = (int)j / 512, k = (int)j % 512;
    Bt3[j] = f2bf(lw[k*128 + n]);
    return;
  }
  j -= 128*512;
  if (j < WTOT) {                              // MLP weights fp16
    float v = 0.f;
    long i = j;
    if (i < 8192)      { int n = i >> 6, k = i & 63;
                         v = (n < 64) ? aw1[k*64 + n] : rw1[k*64 + (n - 64)]; }
    else if ((i -= 8192) < 4096) { int n = i >> 6, k = i & 63; v = aw2[k*64 + n]; }
    else if ((i -= 4096) < 1024) { int n = i >> 6, k = i & 63; v = (n < 4) ? aw3[k*4 + n] : 0.f; }
    else if ((i -= 1024) < 4096) { int n = i >> 6, k = i & 63; v = rw2[k*64 + n]; }
    else if ((i -= 4096) < 4096) { int n = i >> 6, k = i & 63; v = sw1[k*64 + n]; }
    else if ((i -= 4096) < 4096) { int n = i >> 6, k = i & 63; v = sw2[k*64 + n]; }
    else               { i -= 4096; int n = i >> 6, k = i & 63; v = sw3[k*32 + n]; }
    W[j] = f2h(v);
  }
}

// ---------------- CSR build -------------------------------------------------
__global__ __launch_bounds__(256) void k_count(const int* __restrict__ edst, int* __restrict__ counts){
  int e = blockIdx.x * 256 + threadIdx.x;
  if (e < EE) atomicAdd(&counts[edst[e]], 1);
}
__global__ __launch_bounds__(1024) void k_scan(const int* __restrict__ counts,
                                               int* __restrict__ offs, int* __restrict__ cursor){
  __shared__ int part[1024];
  int t = threadIdx.x;
  int c0 = t * 20, c1 = c0 + 20; if (c1 > NN) c1 = NN; if (c0 > NN) c0 = NN;
  int s = 0;
  for (int i = c0; i < c1; ++i) s += counts[i];
  part[t] = s;
  __syncthreads();
  int acc = s;
  #pragma unroll
  for (int d = 1; d < 1024; d <<= 1) {
    int v = (t >= d) ? part[t - d] : 0;
    __syncthreads();
    acc += v;
    part[t] = acc;
    __syncthreads();
  }
  if (t == 1023) offs[NN] = acc;
  int run = acc - s;
  for (int i = c0; i < c1; ++i) { offs[i] = run; cursor[i] = run; run += counts[i]; }
}
__global__ __launch_bounds__(256) void k_fill(const int* __restrict__ edst,
                                              int* __restrict__ cursor, int* __restrict__ eids){
  int e = blockIdx.x * 256 + threadIdx.x;
  if (e < EE) { int p = atomicAdd(&cursor[edst[e]], 1); eids[p] = e; }
}
// wave-parallel deterministic rank sort (deg<=64 fast path)
__global__ __launch_bounds__(256) void k_sort2(const int* __restrict__ offs, int* __restrict__ eids){
  int w = threadIdx.x >> 6, lane = threadIdx.x & 63;
  int n = blockIdx.x * 4 + w;
  if (n >= NN) return;
  int beg = offs[n], end = offs[n+1], deg = end - beg;
  if (deg <= 1) return;
  if (deg <= 64) {
    int v = (lane < deg) ? eids[beg + lane] : 0x7fffffff;
    int rank = 0;
    for (int j = 0; j < deg; ++j) {
      int u = __shfl(v, j);
      rank += (u < v) ? 1 : 0;
    }
    if (lane < deg) eids[beg + rank] = v;
  } else if (lane == 0) {
    for (int i = beg + 1; i < end; ++i) {
      int v = eids[i]; int j = i - 1;
      while (j >= beg && eids[j] > v) { eids[j+1] = eids[j]; --j; }
      eids[j+1] = v;
    }
  }
}

// ---------------- FP16 MFMA MLP building blocks (stride 72, 16B-aligned) ----
template<int NI>
__device__ __forceinline__ void gemm16_lds(const u16 (*X)[72], int wrow, int lane,
                                           const u16* __restrict__ B, f32x4 acc[2][4])
{
  const int fr = lane & 15, fc = lane >> 4;
  #pragma unroll
  for (int mi = 0; mi < 2; ++mi)
    #pragma unroll
    for (int ni = 0; ni < NI; ++ni)
      acc[mi][ni] = (f32x4){0.f, 0.f, 0.f, 0.f};
  #pragma unroll
  for (int kk = 0; kk < 2; ++kk) {
    f16x8 a0 = *(const f16x8*)&X[wrow + fr][kk*32 + fc*8];
    f16x8 a1 = *(const f16x8*)&X[wrow + 16 + fr][kk*32 + fc*8];
    #pragma unroll
    for (int ni = 0; ni < NI; ++ni) {
      f16x8 b = *(const f16x8*)(B + (size_t)(ni*16 + fr)*64 + kk*32 + fc*8);
      acc[0][ni] = __builtin_amdgcn_mfma_f32_16x16x32_f16(a0, b, acc[0][ni], 0, 0, 0);
      acc[1][ni] = __builtin_amdgcn_mfma_f32_16x16x32_f16(a1, b, acc[1][ni], 0, 0, 0);
    }
  }
}

// 1-row-block (16 rows/wave) LDS gemm for the fused s-MLP tail.
template<int NI>
__device__ __forceinline__ void gemm16_lds1(const u16 (*X)[72], int wrow, int lane,
                                            const u16* __restrict__ B, f32x4 acc[4])
{
  const int fr = lane & 15, fc = lane >> 4;
  #pragma unroll
  for (int ni = 0; ni < NI; ++ni) acc[ni] = (f32x4){0.f, 0.f, 0.f, 0.f};
  #pragma unroll
  for (int kk = 0; kk < 2; ++kk) {
    f16x8 a = *(const f16x8*)&X[wrow + fr][kk*32 + fc*8];
    #pragma unroll
    for (int ni = 0; ni < NI; ++ni) {
      f16x8 b = *(const f16x8*)(B + (size_t)(ni*16 + fr)*64 + kk*32 + fc*8);
      acc[ni] = __builtin_amdgcn_mfma_f32_16x16x32_f16(a, b, acc[ni], 0, 0, 0);
    }
  }
}

// NI-col gemm, A from global fp16 plane (row stride 64)
template<int NI>
__device__ __forceinline__ void gemm16_glb(const u16* __restrict__ X, int row0, int lane,
                                           const u16* __restrict__ B, f32x4 acc[2][4])
{
  const int fr = lane & 15, fc = lane >> 4;
  #pragma unroll
  for (int mi = 0; mi < 2; ++mi)
    #pragma unroll
    for (int ni = 0; ni < NI; ++ni)
      acc[mi][ni] = (f32x4){0.f, 0.f, 0.f, 0.f};
  #pragma unroll
  for (int kk = 0; kk < 2; ++kk) {
    f16x8 a0 = *(const f16x8*)(X + (size_t)(row0 + fr)*64 + kk*32 + fc*8);
    f16x8 a1 = *(const f16x8*)(X + (size_t)(row0 + 16 + fr)*64 + kk*32 + fc*8);
    #pragma unroll
    for (int ni = 0; ni < NI; ++ni) {
      f16x8 b = *(const f16x8*)(B + (size_t)(ni*16 + fr)*64 + kk*32 + fc*8);
      acc[0][ni] = __builtin_amdgcn_mfma_f32_16x16x32_f16(a0, b, acc[0][ni], 0, 0, 0);
      acc[1][ni] = __builtin_amdgcn_mfma_f32_16x16x32_f16(a1, b, acc[1][ni], 0, 0, 0);
    }
  }
}

// bias (+ optional LN) + SiLU on 2-row-block C fragments, store fp16
template<bool LN>
__device__ __forceinline__ void act_store16(f32x4 acc[2][4],
    const float* __restrict__ b, const float* __restrict__ g, const float* __restrict__ be,
    u16 (*H)[72], int wrow, int lane)
{
  const int fr = lane & 15, fc = lane >> 4;
  float bv[4], gv[4], bev[4];
  #pragma unroll
  for (int ni = 0; ni < 4; ++ni) {
    bv[ni] = b[ni*16 + fr];
    if (LN) { gv[ni] = g[ni*16 + fr]; bev[ni] = be[ni*16 + fr]; }
  }
  #pragma unroll
  for (int mi = 0; mi < 2; ++mi)
    #pragma unroll
    for (int j = 0; j < 4; ++j) {
      int r = wrow + mi*16 + fc*4 + j;
      float x[4];
      #pragma unroll
      for (int ni = 0; ni < 4; ++ni) x[ni] = acc[mi][ni][j] + bv[ni];
      if (LN) {
        float s  = x[0] + x[1] + x[2] + x[3];
        float s2 = x[0]*x[0] + x[1]*x[1] + x[2]*x[2] + x[3]*x[3];
        #pragma unroll
        for (int off = 1; off < 16; off <<= 1) {
          s  += __shfl_xor(s,  off);
          s2 += __shfl_xor(s2, off);
        }
        float mu  = s * (1.f/64.f);
        float var = s2 * (1.f/64.f) - mu*mu;
        float rs  = rsqrtf(var + 1e-6f);
        #pragma unroll
        for (int ni = 0; ni < 4; ++ni) x[ni] = (x[ni] - mu)*rs*gv[ni] + bev[ni];
      }
      #pragma unroll
      for (int ni = 0; ni < 4; ++ni)
        H[r][ni*16 + fr] = f2h(fsilu(x[ni]));
    }
}

// 1-row-block version (fused s-MLP tail)
template<bool LN>
__device__ __forceinline__ void act_store16_1(f32x4 acc[4],
    const float* __restrict__ b, const float* __restrict__ g, const float* __restrict__ be,
    u16 (*H)[72], int wrow, int lane)
{
  const int fr = lane & 15, fc = lane >> 4;
  float bv[4], gv[4], bev[4];
  #pragma unroll
  for (int ni = 0; ni < 4; ++ni) {
    bv[ni] = b[ni*16 + fr];
    if (LN) { gv[ni] = g[ni*16 + fr]; bev[ni] = be[ni*16 + fr]; }
  }
  #pragma unroll
  for (int j = 0; j < 4; ++j) {
    int r = wrow + fc*4 + j;
    float x[4];
    #pragma unroll
    for (int ni = 0; ni < 4; ++ni) x[ni] = acc[ni][j] + bv[ni];
    if (LN) {
      float s  = x[0] + x[1] + x[2] + x[3];
      float s2 = x[0]*x[0] + x[1]*x[1] + x[2]*x[2] + x[3]*x[3];
      #pragma unroll
      for (int off = 1; off < 16; off <<= 1) {
        s  += __shfl_xor(s,  off);
        s2 += __shfl_xor(s2, off);
      }
      float mu  = s * (1.f/64.f);
      float var = s2 * (1.f/64.f) - mu*mu;
      float rs  = rsqrtf(var + 1e-6f);
      #pragma unroll
      for (int ni = 0; ni < 4; ++ni) x[ni] = (x[ni] - mu)*rs*gv[ni] + bev[ni];
    }
    #pragma unroll
    for (int ni = 0; ni < 4; ++ni)
      H[r][ni*16 + fr] = f2h(fsilu(x[ni]));
  }
}

// ---- K_EDGE1: fused {alpha MLP, radial MLP} then {G1 msg GEMM} -------------
// Single H buffer: alpha chain then radial chain reuse it (wave-private rows).
union ESmem {
  struct { u16 H[128][72]; } m;                     // 18432 B (MLP phase)
  struct { u16 Bs[2][128][40]; } g;                 // 20480 B (GEMM phase, dbuf)
};
__global__ __launch_bounds__(256, 6) void k_edge1(
  const u16* __restrict__ elen16, const float* __restrict__ esh,
  const u16* __restrict__ Wm,
  const float* __restrict__ ab1, const float* __restrict__ ag1, const float* __restrict__ abe1,
  const float* __restrict__ ab2, const float* __restrict__ ag2, const float* __restrict__ abe2,
  const float* __restrict__ ab3,
  const float* __restrict__ tb1, const float* __restrict__ tb2,
  float* __restrict__ ealpha_g, float* __restrict__ scal_g, float* __restrict__ cbuf_g,
  const u16* __restrict__ node16,
  const int* __restrict__ esrc, const int* __restrict__ edst,
  const u16* __restrict__ Bt1, u16* __restrict__ msgb)
{
  __shared__ ESmem u;
  __shared__ float aS[128][4];
  const u16* Wa1 = Wm;            // alpha L1 (outs 0..63 of combined block)
  const u16* Wr1 = Wm + 4096;     // radial L1 (outs 64..127)
  const u16* Wa2 = Wm + 8192;
  const u16* Wa3 = Wm + 12288;
  const u16* Wr2 = Wm + 13312;
  const int tid = threadIdx.x;
  const int wave = tid >> 6, lane = tid & 63;
  const int fr = lane & 15, fc = lane >> 4;
  const int wrow = wave * 32;
  const int e0 = blockIdx.x * 128;
  // ================= phase A: alpha chain then radial chain (one H buffer) =
  {
    f32x4 acc[2][4];
    // alpha L1 (A from global)
    gemm16_glb<4>(elen16, e0 + wrow, lane, Wa1, acc);
    act_store16<true>(acc, ab1, ag1, abe1, u.m.H, wrow, lane);
    // alpha L2 (in-place on H)
    gemm16_lds<4>(u.m.H, wrow, lane, Wa2, acc);
    act_store16<true>(acc, ab2, ag2, abe2, u.m.H, wrow, lane);
    // alpha L3: N=4 (padded to 16); store exp(alpha) (softmax shift-free)
    gemm16_lds<1>(u.m.H, wrow, lane, Wa3, acc);
    {
      float bv = (fr < 4) ? ab3[fr] : 0.f;
      #pragma unroll
      for (int mi = 0; mi < 2; ++mi)
        #pragma unroll
        for (int j = 0; j < 4; ++j) {
          int r = wrow + mi*16 + fc*4 + j;
          float v = acc[mi][0][j] + bv;
          if (fr < 4) {
            ealpha_g[(size_t)(e0 + r)*4 + fr] = __expf(v);
            aS[r][fr] = v;
          }
        }
    }
    // radial L1 (A from global again, L2-warm; overwrites H)
    gemm16_glb<4>(elen16, e0 + wrow, lane, Wr1, acc);
    act_store16<false>(acc, tb1, nullptr, nullptr, u.m.H, wrow, lane);
    // radial L2 + sh contraction
    gemm16_lds<4>(u.m.H, wrow, lane, Wr2, acc);
    {
      float bv[4];
      #pragma unroll
      for (int ni = 0; ni < 4; ++ni) bv[ni] = tb2[ni*16 + fr];
      #pragma unroll
      for (int mi = 0; mi < 2; ++mi)
        #pragma unroll
        for (int j = 0; j < 4; ++j) {
          int r = wrow + mi*16 + fc*4 + j;
          float shv = esh[(size_t)(e0 + r)*16 + fr];
          float sc[4];
          #pragma unroll
          for (int ni = 0; ni < 4; ++ni) {
            float t = (acc[mi][ni][j] + bv[ni]) * shv;
            #pragma unroll
            for (int off = 1; off < 16; off <<= 1) t += __shfl_xor(t, off);
            sc[ni] = t;
          }
          if (fr == 0) {
            float4 sv; sv.x = sc[0]; sv.y = sc[1]; sv.z = sc[2]; sv.w = sc[3];
            *(float4*)(scal_g + (size_t)(e0 + r)*4) = sv;
            float4 cv;
            cv.x = sc[0]*aS[r][0]; cv.y = sc[1]*aS[r][1];
            cv.z = sc[2]*aS[r][2]; cv.w = sc[3]*aS[r][3];
            *(float4*)(cbuf_g + (size_t)(e0 + r)*4) = cv;
          }
        }
    }
  }
  __syncthreads();   // phase join: H reads done, Bs aliases it
  // ====== phase B: msg GEMM — wave owns 32 rows x 128 cols; A per-lane =====
  {
    const int r0 = e0 + wrow + fr;          // lane-private edge rows
    const int r1 = r0 + 16;
    const int s0 = esrc[r0], d0 = edst[r0];
    const int s1 = esrc[r1], d1 = edst[r1];
    const int sr = tid >> 1, sh = tid & 1;  // B staging: row sr, cols sh*16..+15
    const u16* bstg = Bt1 + (size_t)sr*320 + sh*16;
    // stage buf0 (k0 = 0)
    {
      const uint4* bp = (const uint4*)(bstg);
      *(uint4*)&u.g.Bs[0][sr][sh*16]     = bp[0];
      *(uint4*)&u.g.Bs[0][sr][sh*16 + 8] = bp[1];
    }
    f32x4 acc[2][8];
    #pragma unroll
    for (int mi = 0; mi < 2; ++mi)
      #pragma unroll
      for (int ni = 0; ni < 8; ++ni)
        acc[mi][ni] = (f32x4){0.f, 0.f, 0.f, 0.f};
    __syncthreads();
    #pragma unroll
    for (int k0i = 0; k0i < 10; ++k0i) {
      const int buf = k0i & 1;
      if (k0i + 1 < 10) {                   // stage next into buf^1
        const uint4* bp = (const uint4*)(bstg + (k0i + 1)*32);
        *(uint4*)&u.g.Bs[buf^1][sr][sh*16]     = bp[0];
        *(uint4*)&u.g.Bs[buf^1][sr][sh*16 + 8] = bp[1];
      }
      // A fragments: lane-private gathered rows (source uniform per k-step)
      const int k0 = k0i * 32;
      const u16 *ap0, *ap1;
      if (k0 < 128)      { ap0 = node16 + (size_t)s0*128 + k0;
                           ap1 = node16 + (size_t)s1*128 + k0; }
      else if (k0 < 256) { ap0 = node16 + (size_t)d0*128 + (k0 - 128);
                           ap1 = node16 + (size_t)d1*128 + (k0 - 128); }
      else               { ap0 = elen16 + (size_t)r0*64 + (k0 - 256);
                           ap1 = elen16 + (size_t)r1*64 + (k0 - 256); }
      f16x8 a0 = *(const f16x8*)(ap0 + fc*8);
      f16x8 a1 = *(const f16x8*)(ap1 + fc*8);
      #pragma unroll
      for (int ni = 0; ni < 8; ++ni) {
        f16x8 b = *(const f16x8*)&u.g.Bs[buf][ni*16 + fr][fc*8];
        acc[0][ni] = __builtin_amdgcn_mfma_f32_16x16x32_f16(a0, b, acc[0][ni], 0, 0, 0);
        acc[1][ni] = __builtin_amdgcn_mfma_f32_16x16x32_f16(a1, b, acc[1][ni], 0, 0, 0);
      }
      __syncthreads();
    }
    #pragma unroll
    for (int mi = 0; mi < 2; ++mi)
      #pragma unroll
      for (int j = 0; j < 4; ++j) {
        int row = wrow + mi*16 + fc*4 + j;
        size_t base = (size_t)(e0 + row)*128 + fr;
        #pragma unroll
        for (int ni = 0; ni < 8; ++ni)
          msgb[base + ni*16] = f2h(acc[mi][ni][j]);
      }
  }
}

// ---- G2S: A in regs (fp16); B plain-staged; fused s-MLP tail ---------------
__global__ __launch_bounds__(256, 4) void g2s(
    const u16* __restrict__ msgb, const u16* __restrict__ Bt2,
    const float* __restrict__ cbuf, const u16* __restrict__ Wm,
    const float* __restrict__ b1, const float* __restrict__ g1, const float* __restrict__ be1,
    const float* __restrict__ b2, const float* __restrict__ g2, const float* __restrict__ be2,
    const float* __restrict__ b3,
    float* __restrict__ oute)
{
  __shared__ u16 Bs[256][40];
  __shared__ u16 X[64][72];
  __shared__ float cS[64][4];
  const u16* Ws1 = Wm + 17408;
  const u16* Ws2 = Wm + 21504;
  const u16* Ws3 = Wm + 25600;
  const int tid = threadIdx.x, wave = tid >> 6, lane = tid & 63;
  const int e0 = blockIdx.x * 64;
  const int fr = lane & 15, fc = lane >> 4;
  const int wrow = wave * 16;
  cS[tid >> 2][tid & 3] = cbuf[(size_t)e0*4 + tid];
  f16x8 a[4];
  {
    const u16* arow = msgb + (size_t)(e0 + wrow + fr)*128 + fc*8;
    #pragma unroll
    for (int k0i = 0; k0i < 4; ++k0i) a[k0i] = *(const f16x8*)(arow + k0i*32);
  }
  f32x4 acc[16];
  #pragma unroll
  for (int ni = 0; ni < 16; ++ni) acc[ni] = (f32x4){0.f, 0.f, 0.f, 0.f};
  const u16* bsrc = Bt2 + (size_t)tid*128;
  #pragma unroll
  for (int k0i = 0; k0i < 4; ++k0i) {
    {
      const uint4* bp = (const uint4*)(bsrc + k0i*32);
      *(uint4*)&Bs[tid][0]  = bp[0];
      *(uint4*)&Bs[tid][8]  = bp[1];
      *(uint4*)&Bs[tid][16] = bp[2];
      *(uint4*)&Bs[tid][24] = bp[3];
    }
    __syncthreads();
    #pragma unroll
    for (int ni = 0; ni < 16; ++ni) {
      f16x8 b = *(const f16x8*)&Bs[ni*16 + fr][fc*8];
      acc[ni] = __builtin_amdgcn_mfma_f32_16x16x32_f16(a[k0i], b, acc[ni], 0, 0, 0);
    }
    __syncthreads();
  }
  // head-sum in-register: y0[m] = sum_h cS[row][h] * acc[4h+m]; write X fp16
  #pragma unroll
  for (int j = 0; j < 4; ++j) {
    int r = wrow + fc*4 + j;
    float c0 = cS[r][0], c1 = cS[r][1], c2 = cS[r][2], c3 = cS[r][3];
    #pragma unroll
    for (int m = 0; m < 4; ++m) {
      float y = c0*acc[m][j] + c1*acc[4+m][j] + c2*acc[8+m][j] + c3*acc[12+m][j];
      X[r][m*16 + fr] = f2h(y);
    }
  }
  // s-MLP tail: wave w owns rows [w*16, w*16+16) of X — barrier-free
  f32x4 sa[4];
  gemm16_lds1<4>(X, wrow, lane, Ws1, sa);
  act_store16_1<true>(sa, b1, g1, be1, X, wrow, lane);
  gemm16_lds1<4>(X, wrow, lane, Ws2, sa);
  act_store16_1<true>(sa, b2, g2, be2, X, wrow, lane);
  gemm16_lds1<2>(X, wrow, lane, Ws3, sa);
  {
    float bv0 = b3[fr], bv1 = b3[16 + fr];
    #pragma unroll
    for (int j = 0; j < 4; ++j) {
      int r = wrow + fc*4 + j;
      oute[(size_t)(e0 + r)*32 + fr]      = sa[0][j] + bv0;
      oute[(size_t)(e0 + r)*32 + 16 + fr] = sa[1][j] + bv1;
    }
  }
}

// ---------------- K9: per-node softmax + aggregation (no-max, exp pre-done) -
__global__ __launch_bounds__(256) void k_node(
  const int* __restrict__ offs, const int* __restrict__ eids,
  const float* __restrict__ ealpha, const float* __restrict__ scal,
  const u16* __restrict__ msgb, u16* __restrict__ nfb)
{
  const int w = threadIdx.x >> 6, lane = threadIdx.x & 63;
  const int n = blockIdx.x * 4 + w;
  const int beg = offs[n], end = offs[n+1];
  float se0=0.f, se1=0.f, se2=0.f, se3=0.f;
  float f00=0.f, f01=0.f, f10=0.f, f11=0.f, f20=0.f, f21=0.f, f30=0.f, f31=0.f;
  for (int i = beg; i < end; ++i) {
    int eid = eids[i];
    float4 a = *(const float4*)(ealpha + (size_t)eid*4);
    float4 s = *(const float4*)(scal + (size_t)eid*4);
    se0 += a.x; se1 += a.y; se2 += a.z; se3 += a.w;
    float w0 = a.x*s.x, w1 = a.y*s.y, w2 = a.z*s.z, w3 = a.w*s.w;
    float v0 = h2f(msgb[(size_t)eid*128 + lane]);
    float v1 = h2f(msgb[(size_t)eid*128 + 64 + lane]);
    f00 = fmaf(w0, v0, f00); f01 = fmaf(w0, v1, f01);
    f10 = fmaf(w1, v0, f10); f11 = fmaf(w1, v1, f11);
    f20 = fmaf(w2, v0, f20); f21 = fmaf(w2, v1, f21);
    f30 = fmaf(w3, v0, f30); f31 = fmaf(w3, v1, f31);
  }
  float i0 = 1.f/(se0 + 1e-16f), i1 = 1.f/(se1 + 1e-16f);
  float i2 = 1.f/(se2 + 1e-16f), i3 = 1.f/(se3 + 1e-16f);
  size_t b = (size_t)n * 512;
  nfb[b + 0*128 + lane]      = f2bf(f00*i0);
  nfb[b + 0*128 + 64 + lane] = f2bf(f01*i0);
  nfb[b + 1*128 + lane]      = f2bf(f10*i1);
  nfb[b + 1*128 + 64 + lane] = f2bf(f11*i1);
  nfb[b + 2*128 + lane]      = f2bf(f20*i2);
  nfb[b + 2*128 + 64 + lane] = f2bf(f21*i2);
  nfb[b + 3*128 + lane]      = f2bf(f30*i3);
  nfb[b + 3*128 + 64 + lane] = f2bf(f31*i3);
}

// ---------------- G10: node_out = node_fea @ lin_w (bf16) -------------------
__global__ __launch_bounds__(256) void g10_out(
    const u16* __restrict__ nfb, const u16* __restrict__ Bt3,
    float* __restrict__ out)
{
  __shared__ u16 As[128][40];
  __shared__ u16 Bs[128][40];
  const int tid = threadIdx.x;
  const int n0 = blockIdx.x * 128;
  const int wave = tid >> 6, lane = tid & 63;
  const int wr = (wave >> 1) * 64, wc = (wave & 1) * 64;
  const int fr = lane & 15, fc = lane >> 4;
  f32x4 acc[4][4] = {};
  const int r = tid >> 1, half = tid & 1;
  const int n = n0 + r;
  for (int k0 = 0; k0 < 512; k0 += 32) {
    uint4 z; z.x=0; z.y=0; z.z=0; z.w=0;
    uint4 v0 = z, v1 = z;
    if (n < NN) {
      const uint4* apv = (const uint4*)(nfb + (size_t)n*512 + k0 + half*16);
      v0 = apv[0]; v1 = apv[1];
    }
    *(uint4*)&As[r][half*16]     = v0;
    *(uint4*)&As[r][half*16 + 8] = v1;
    const uint4* bp = (const uint4*)(Bt3 + (size_t)r*512 + k0 + half*16);
    *(uint4*)&Bs[r][half*16]     = bp[0];
    *(uint4*)&Bs[r][half*16 + 8] = bp[1];
    __syncthreads();
    bf16x8 a[4], b[4];
    #pragma unroll
    for (int mi = 0; mi < 4; ++mi) a[mi] = *(const bf16x8*)&As[wr + mi*16 + fr][fc*8];
    #pragma unroll
    for (int ni = 0; ni < 4; ++ni) b[ni] = *(const bf16x8*)&Bs[wc + ni*16 + fr][fc*8];
    #pragma unroll
    for (int mi = 0; mi < 4; ++mi)
      #pragma unroll
      for (int ni = 0; ni < 4; ++ni)
        acc[mi][ni] = __builtin_amdgcn_mfma_f32_16x16x32_bf16(a[mi], b[ni], acc[mi][ni], 0, 0, 0);
    __syncthreads();
  }
  #pragma unroll
  for (int mi = 0; mi < 4; ++mi)
    #pragma unroll
    for (int j = 0; j < 4; ++j) {
      int rowg = n0 + wr + mi*16 + fc*4 + j;
      if (rowg < NN) {
        size_t base = (size_t)rowg*128 + wc + fr;
        #pragma unroll
        for (int ni = 0; ni < 4; ++ni)
          out[base + ni*16] = acc[mi][ni][j];
      }
    }
}

// ---------------- launch ----------------------------------------------------
extern "C" void kernel_launch(void* const* d_in, const int* in_sizes, int n_in,
                              void* d_out, int out_size, void* d_ws, size_t ws_size,
                              hipStream_t stream)
{
  const float* node_in    = (const float*)d_in[0];
  const float* edge_sh    = (const float*)d_in[2];
  const float* elen       = (const float*)d_in[3];
  const int*   esrc       = (const int*)d_in[4];
  const int*   edst       = (const int*)d_in[5];
  const float* pre_lin_w  = (const float*)d_in[7];
  const float* tp2_w1     = (const float*)d_in[8];
  const float* tp2_b1     = (const float*)d_in[9];
  const float* tp2_w2     = (const float*)d_in[10];
  const float* tp2_b2     = (const float*)d_in[11];
  const float* a_w1  = (const float*)d_in[12];
  const float* a_b1  = (const float*)d_in[13];
  const float* a_g1  = (const float*)d_in[14];
  const float* a_be1 = (const float*)d_in[15];
  const float* a_w2  = (const float*)d_in[16];
  const float* a_b2  = (const float*)d_in[17];
  const float* a_g2  = (const float*)d_in[18];
  const float* a_be2 = (const float*)d_in[19];
  const float* a_w3  = (const float*)d_in[20];
  const float* a_b3  = (const float*)d_in[21];
  const float* lin_w      = (const float*)d_in[22];
  const float* lin_edge_w = (const float*)d_in[23];
  const float* s_w1  = (const float*)d_in[24];
  const float* s_b1  = (const float*)d_in[25];
  const float* s_g1  = (const float*)d_in[26];
  const float* s_be1 = (const float*)d_in[27];
  const float* s_w2  = (const float*)d_in[28];
  const float* s_b2  = (const float*)d_in[29];
  const float* s_g2  = (const float*)d_in[30];
  const float* s_be2 = (const float*)d_in[31];
  const float* s_w3  = (const float*)d_in[32];
  const float* s_b3  = (const float*)d_in[33];

  float* out_node = (float*)d_out;
  float* out_edge = out_node + (size_t)NN * 128;

  char* ws = (char*)d_ws;
  size_t off = 0;
  auto take = [&](size_t bytes) -> char* {
    char* p = ws + off;
    off = (off + bytes + 255) & ~(size_t)255;
    return p;
  };
  u16*   msgb   = (u16*)take((size_t)EE * 128 * 2);
  u16*   elen16 = (u16*)take((size_t)EE * 64 * 2);
  u16*   node16 = (u16*)take((size_t)NN * 128 * 2);
  u16*   nfb    = (u16*)take((size_t)NN * 512 * 2);
  float* ealpha = (float*)take((size_t)EE * 4 * 4);
  float* scal   = (float*)take((size_t)EE * 4 * 4);
  float* cbuf   = (float*)take((size_t)EE * 4 * 4);
  int*   counts = (int*)take((size_t)NN * 4);
  int*   offs   = (int*)take((size_t)(NN + 1) * 4);
  int*   cursor = (int*)take((size_t)NN * 4);
  int*   eids   = (int*)take((size_t)EE * 4);
  u16*   Bt1    = (u16*)take((size_t)128 * 320 * 2);
  u16*   Bt2    = (u16*)take((size_t)256 * 128 * 2);
  u16*   Bt3    = (u16*)take((size_t)128 * 512 * 2);
  u16*   Wmlp   = (u16*)take((size_t)WTOT * 2);

  const long prep_total = (long)P3N + NN + 128*320 + 256*128 + 128*512 + WTOT;
  k_prep_all<<<(int)((prep_total + 255)/256), 256, 0, stream>>>(
      elen, node_in, elen16, node16, counts,
      pre_lin_w, lin_edge_w, lin_w, Bt1, Bt2, Bt3,
      a_w1, a_w2, a_w3, tp2_w1, tp2_w2, s_w1, s_w2, s_w3, Wmlp);
  k_count<<<EE/256, 256, 0, stream>>>(edst, counts);
  k_scan<<<1, 1024, 0, stream>>>(counts, offs, cursor);
  k_fill<<<EE/256, 256, 0, stream>>>(edst, cursor, eids);
  k_sort2<<<NN/4, 256, 0, stream>>>(offs, eids);
  k_edge1<<<EE/128, 256, 0, stream>>>(elen16, edge_sh, Wmlp,
                                      a_b1, a_g1, a_be1, a_b2, a_g2, a_be2, a_b3,
                                      tp2_b1, tp2_b2, ealpha, scal, cbuf,
                                      node16, esrc, edst, Bt1, msgb);
  g2s<<<EE/64, 256, 0, stream>>>(msgb, Bt2, cbuf, Wmlp,
                                 s_b1, s_g1, s_be1, s_b2, s_g2, s_be2, s_b3, out_edge);
  k_node<<<NN/4, 256, 0, stream>>>(offs, eids, ealpha, scal, msgb, nfb);
  g10_out<<<(NN + 127)/128, 256, 0, stream>>>(nfb, Bt3, out_node);
}

// Round 23
// 394.971 us; speedup vs baseline: 1.4289x; 1.4289x over previous
//
#include <hip/hip_runtime.h>

#define NN 20000
#define EE 320000
#define WTOT 27648
#define P3N (EE*64/8 + NN*128/8)

typedef unsigned short u16;
typedef unsigned int u32;
typedef __attribute__((ext_vector_type(8))) short bf16x8;
typedef __attribute__((ext_vector_type(8))) _Float16 f16x8;
typedef __attribute__((ext_vector_type(4))) float f32x4;

__device__ __forceinline__ float bf2f(u16 u){
  union { u32 i; float f; } v; v.i = ((u32)u) << 16; return v.f;
}
__device__ __forceinline__ u16 f2bf(float f){
  union { float f; u32 i; } v; v.f = f;
  u32 i = v.i;
  return (u16)((i + 0x7FFFu + ((i >> 16) & 1u)) >> 16);
}
__device__ __forceinline__ u16 f2h(float f){
  union { _Float16 h[2]; u32 u; } v; v.h[0] = (_Float16)f;
  return (u16)(v.u & 0xFFFF);
}
__device__ __forceinline__ float h2f(u16 u){
  union { u32 i; _Float16 h[2]; } v; v.i = u; return (float)v.h[0];
}
__device__ __forceinline__ u32 packh2(float a, float b){
  return ((u32)f2h(b) << 16) | (u32)f2h(a);
}
__device__ __forceinline__ float fsilu(float y){
  return y * __builtin_amdgcn_rcpf(1.f + __expf(-y));
}

// ---- merged prep: fp16 planes + counts zero + weight transposes ------------
__global__ __launch_bounds__(256) void k_prep_all(
    const float* __restrict__ elen, const float* __restrict__ node_in,
    u16* __restrict__ elen16, u16* __restrict__ node16,
    int* __restrict__ counts,
    const float* __restrict__ plw, const float* __restrict__ lew,
    const float* __restrict__ lw,
    u16* __restrict__ Bt1, u16* __restrict__ Bt2, u16* __restrict__ Bt3,
    const float* __restrict__ aw1, const float* __restrict__ aw2, const float* __restrict__ aw3,
    const float* __restrict__ rw1, const float* __restrict__ rw2,
    const float* __restrict__ sw1, const float* __restrict__ sw2, const float* __restrict__ sw3,
    u16* __restrict__ W)
{
  size_t gi = (size_t)blockIdx.x * 256 + threadIdx.x;
  if (gi < (size_t)P3N) {                      // fp32 -> fp16 planes (8/thread)
    const size_t n1 = (size_t)EE * 64 / 8;
    const float* src;
    u16* dst;
    if (gi < n1) { src = elen + gi*8; dst = elen16 + gi*8; }
    else { size_t j = gi - n1; src = node_in + j*8; dst = node16 + j*8; }
    float4 a = ((const float4*)src)[0];
    float4 b = ((const float4*)src)[1];
    uint4 vh;
    vh.x = packh2(a.x, a.y); vh.y = packh2(a.z, a.w);
    vh.z = packh2(b.x, b.y); vh.w = packh2(b.z, b.w);
    *(uint4*)dst = vh;
    return;
  }
  long j = (long)gi - P3N;
  if (j < NN) { counts[j] = 0; return; }
  j -= NN;
  if (j < 128*320) {                           // Bt1[n][k] = pre_lin_w[k][n]
    int n = (int)j / 320, k = (int)j % 320;
    Bt1[j] = f2h(plw[k*128 + n]);
    return;
  }
  j -= 128*320;
  if (j < 256*128) {                           // Bt2[h*64+c][k]
    int n = (int)j / 128, k = (int)j % 128;
    int h = n >> 6, c = n & 63;
    Bt2[j] = f2h(lew[(h*128 + k)*64 + c]);
    return;
  }
  j -= 256*128;
  if (j < 128*512) {                           // Bt3[n][k] = lin_w[k][n]
    int n = (int)j / 512, k = (int)j % 512;
    Bt3[j] = f2bf(lw[k*128 + n]);
    return;
  }
  j -= 128*512;
  if (j < WTOT) {                              // MLP weights fp16
    float v = 0.f;
    long i = j;
    if (i < 8192)      { int n = i >> 6, k = i & 63;
                         v = (n < 64) ? aw1[k*64 + n] : rw1[k*64 + (n - 64)]; }
    else if ((i -= 8192) < 4096) { int n = i >> 6, k = i & 63; v = aw2[k*64 + n]; }
    else if ((i -= 4096) < 1024) { int n = i >> 6, k = i & 63; v = (n < 4) ? aw3[k*4 + n] : 0.f; }
    else if ((i -= 1024) < 4096) { int n = i >> 6, k = i & 63; v = rw2[k*64 + n]; }
    else if ((i -= 4096) < 4096) { int n = i >> 6, k = i & 63; v = sw1[k*64 + n]; }
    else if ((i -= 4096) < 4096) { int n = i >> 6, k = i & 63; v = sw2[k*64 + n]; }
    else               { i -= 4096; int n = i >> 6, k = i & 63; v = sw3[k*32 + n]; }
    W[j] = f2h(v);
  }
}

// ---------------- CSR build -------------------------------------------------
__global__ __launch_bounds__(256) void k_count(const int* __restrict__ edst, int* __restrict__ counts){
  int e = blockIdx.x * 256 + threadIdx.x;
  if (e < EE) atomicAdd(&counts[edst[e]], 1);
}
__global__ __launch_bounds__(1024) void k_scan(const int* __restrict__ counts,
                                               int* __restrict__ offs, int* __restrict__ cursor){
  __shared__ int part[1024];
  int t = threadIdx.x;
  int c0 = t * 20, c1 = c0 + 20; if (c1 > NN) c1 = NN; if (c0 > NN) c0 = NN;
  int s = 0;
  for (int i = c0; i < c1; ++i) s += counts[i];
  part[t] = s;
  __syncthreads();
  int acc = s;
  #pragma unroll
  for (int d = 1; d < 1024; d <<= 1) {
    int v = (t >= d) ? part[t - d] : 0;
    __syncthreads();
    acc += v;
    part[t] = acc;
    __syncthreads();
  }
  if (t == 1023) offs[NN] = acc;
  int run = acc - s;
  for (int i = c0; i < c1; ++i) { offs[i] = run; cursor[i] = run; run += counts[i]; }
}
__global__ __launch_bounds__(256) void k_fill(const int* __restrict__ edst,
                                              int* __restrict__ cursor, int* __restrict__ eids){
  int e = blockIdx.x * 256 + threadIdx.x;
  if (e < EE) { int p = atomicAdd(&cursor[edst[e]], 1); eids[p] = e; }
}
// wave-parallel deterministic rank sort (deg<=64 fast path)
__global__ __launch_bounds__(256) void k_sort2(const int* __restrict__ offs, int* __restrict__ eids){
  int w = threadIdx.x >> 6, lane = threadIdx.x & 63;
  int n = blockIdx.x * 4 + w;
  if (n >= NN) return;
  int beg = offs[n], end = offs[n+1], deg = end - beg;
  if (deg <= 1) return;
  if (deg <= 64) {
    int v = (lane < deg) ? eids[beg + lane] : 0x7fffffff;
    int rank = 0;
    for (int j = 0; j < deg; ++j) {
      int u = __shfl(v, j);
      rank += (u < v) ? 1 : 0;
    }
    if (lane < deg) eids[beg + rank] = v;
  } else if (lane == 0) {
    for (int i = beg + 1; i < end; ++i) {
      int v = eids[i]; int j = i - 1;
      while (j >= beg && eids[j] > v) { eids[j+1] = eids[j]; --j; }
      eids[j+1] = v;
    }
  }
}

// ---------------- FP16 MFMA MLP building blocks (stride 72, 16B-aligned) ----
template<int NI>
__device__ __forceinline__ void gemm16_lds(const u16 (*X)[72], int wrow, int lane,
                                           const u16* __restrict__ B, f32x4 acc[2][4])
{
  const int fr = lane & 15, fc = lane >> 4;
  #pragma unroll
  for (int mi = 0; mi < 2; ++mi)
    #pragma unroll
    for (int ni = 0; ni < NI; ++ni)
      acc[mi][ni] = (f32x4){0.f, 0.f, 0.f, 0.f};
  #pragma unroll
  for (int kk = 0; kk < 2; ++kk) {
    f16x8 a0 = *(const f16x8*)&X[wrow + fr][kk*32 + fc*8];
    f16x8 a1 = *(const f16x8*)&X[wrow + 16 + fr][kk*32 + fc*8];
    #pragma unroll
    for (int ni = 0; ni < NI; ++ni) {
      f16x8 b = *(const f16x8*)(B + (size_t)(ni*16 + fr)*64 + kk*32 + fc*8);
      acc[0][ni] = __builtin_amdgcn_mfma_f32_16x16x32_f16(a0, b, acc[0][ni], 0, 0, 0);
      acc[1][ni] = __builtin_amdgcn_mfma_f32_16x16x32_f16(a1, b, acc[1][ni], 0, 0, 0);
    }
  }
}

// 1-row-block (16 rows/wave) LDS gemm for the fused s-MLP tail.
template<int NI>
__device__ __forceinline__ void gemm16_lds1(const u16 (*X)[72], int wrow, int lane,
                                            const u16* __restrict__ B, f32x4 acc[4])
{
  const int fr = lane & 15, fc = lane >> 4;
  #pragma unroll
  for (int ni = 0; ni < NI; ++ni) acc[ni] = (f32x4){0.f, 0.f, 0.f, 0.f};
  #pragma unroll
  for (int kk = 0; kk < 2; ++kk) {
    f16x8 a = *(const f16x8*)&X[wrow + fr][kk*32 + fc*8];
    #pragma unroll
    for (int ni = 0; ni < NI; ++ni) {
      f16x8 b = *(const f16x8*)(B + (size_t)(ni*16 + fr)*64 + kk*32 + fc*8);
      acc[ni] = __builtin_amdgcn_mfma_f32_16x16x32_f16(a, b, acc[ni], 0, 0, 0);
    }
  }
}

// NI-col gemm, A from global fp16 plane (row stride 64)
template<int NI>
__device__ __forceinline__ void gemm16_glb(const u16* __restrict__ X, int row0, int lane,
                                           const u16* __restrict__ B, f32x4 acc[2][4])
{
  const int fr = lane & 15, fc = lane >> 4;
  #pragma unroll
  for (int mi = 0; mi < 2; ++mi)
    #pragma unroll
    for (int ni = 0; ni < NI; ++ni)
      acc[mi][ni] = (f32x4){0.f, 0.f, 0.f, 0.f};
  #pragma unroll
  for (int kk = 0; kk < 2; ++kk) {
    f16x8 a0 = *(const f16x8*)(X + (size_t)(row0 + fr)*64 + kk*32 + fc*8);
    f16x8 a1 = *(const f16x8*)(X + (size_t)(row0 + 16 + fr)*64 + kk*32 + fc*8);
    #pragma unroll
    for (int ni = 0; ni < NI; ++ni) {
      f16x8 b = *(const f16x8*)(B + (size_t)(ni*16 + fr)*64 + kk*32 + fc*8);
      acc[0][ni] = __builtin_amdgcn_mfma_f32_16x16x32_f16(a0, b, acc[0][ni], 0, 0, 0);
      acc[1][ni] = __builtin_amdgcn_mfma_f32_16x16x32_f16(a1, b, acc[1][ni], 0, 0, 0);
    }
  }
}

// bias (+ optional LN) + SiLU on 2-row-block C fragments, store fp16
template<bool LN>
__device__ __forceinline__ void act_store16(f32x4 acc[2][4],
    const float* __restrict__ b, const float* __restrict__ g, const float* __restrict__ be,
    u16 (*H)[72], int wrow, int lane)
{
  const int fr = lane & 15, fc = lane >> 4;
  float bv[4], gv[4], bev[4];
  #pragma unroll
  for (int ni = 0; ni < 4; ++ni) {
    bv[ni] = b[ni*16 + fr];
    if (LN) { gv[ni] = g[ni*16 + fr]; bev[ni] = be[ni*16 + fr]; }
  }
  #pragma unroll
  for (int mi = 0; mi < 2; ++mi)
    #pragma unroll
    for (int j = 0; j < 4; ++j) {
      int r = wrow + mi*16 + fc*4 + j;
      float x[4];
      #pragma unroll
      for (int ni = 0; ni < 4; ++ni) x[ni] = acc[mi][ni][j] + bv[ni];
      if (LN) {
        float s  = x[0] + x[1] + x[2] + x[3];
        float s2 = x[0]*x[0] + x[1]*x[1] + x[2]*x[2] + x[3]*x[3];
        #pragma unroll
        for (int off = 1; off < 16; off <<= 1) {
          s  += __shfl_xor(s,  off);
          s2 += __shfl_xor(s2, off);
        }
        float mu  = s * (1.f/64.f);
        float var = s2 * (1.f/64.f) - mu*mu;
        float rs  = rsqrtf(var + 1e-6f);
        #pragma unroll
        for (int ni = 0; ni < 4; ++ni) x[ni] = (x[ni] - mu)*rs*gv[ni] + bev[ni];
      }
      #pragma unroll
      for (int ni = 0; ni < 4; ++ni)
        H[r][ni*16 + fr] = f2h(fsilu(x[ni]));
    }
}

// 1-row-block version (fused s-MLP tail)
template<bool LN>
__device__ __forceinline__ void act_store16_1(f32x4 acc[4],
    const float* __restrict__ b, const float* __restrict__ g, const float* __restrict__ be,
    u16 (*H)[72], int wrow, int lane)
{
  const int fr = lane & 15, fc = lane >> 4;
  float bv[4], gv[4], bev[4];
  #pragma unroll
  for (int ni = 0; ni < 4; ++ni) {
    bv[ni] = b[ni*16 + fr];
    if (LN) { gv[ni] = g[ni*16 + fr]; bev[ni] = be[ni*16 + fr]; }
  }
  #pragma unroll
  for (int j = 0; j < 4; ++j) {
    int r = wrow + fc*4 + j;
    float x[4];
    #pragma unroll
    for (int ni = 0; ni < 4; ++ni) x[ni] = acc[ni][j] + bv[ni];
    if (LN) {
      float s  = x[0] + x[1] + x[2] + x[3];
      float s2 = x[0]*x[0] + x[1]*x[1] + x[2]*x[2] + x[3]*x[3];
      #pragma unroll
      for (int off = 1; off < 16; off <<= 1) {
        s  += __shfl_xor(s,  off);
        s2 += __shfl_xor(s2, off);
      }
      float mu  = s * (1.f/64.f);
      float var = s2 * (1.f/64.f) - mu*mu;
      float rs  = rsqrtf(var + 1e-6f);
      #pragma unroll
      for (int ni = 0; ni < 4; ++ni) x[ni] = (x[ni] - mu)*rs*gv[ni] + bev[ni];
    }
    #pragma unroll
    for (int ni = 0; ni < 4; ++ni)
      H[r][ni*16 + fr] = f2h(fsilu(x[ni]));
  }
}

// ---- K_EDGE1: fused {alpha MLP, radial MLP} then {G1 msg GEMM} -------------
// Single H buffer: alpha chain then radial chain reuse it (wave-private rows).
union ESmem {
  struct { u16 H[128][72]; } m;                     // 18432 B (MLP phase)
  struct { u16 Bs[2][128][40]; } g;                 // 20480 B (GEMM phase, dbuf)
};
__global__ __launch_bounds__(256, 4) void k_edge1(
  const u16* __restrict__ elen16, const float* __restrict__ esh,
  const u16* __restrict__ Wm,
  const float* __restrict__ ab1, const float* __restrict__ ag1, const float* __restrict__ abe1,
  const float* __restrict__ ab2, const float* __restrict__ ag2, const float* __restrict__ abe2,
  const float* __restrict__ ab3,
  const float* __restrict__ tb1, const float* __restrict__ tb2,
  float* __restrict__ ealpha_g, float* __restrict__ scal_g, float* __restrict__ cbuf_g,
  const u16* __restrict__ node16,
  const int* __restrict__ esrc, const int* __restrict__ edst,
  const u16* __restrict__ Bt1, u16* __restrict__ msgb)
{
  __shared__ ESmem u;
  __shared__ float aS[128][4];
  const u16* Wa1 = Wm;            // alpha L1 (outs 0..63 of combined block)
  const u16* Wr1 = Wm + 4096;     // radial L1 (outs 64..127)
  const u16* Wa2 = Wm + 8192;
  const u16* Wa3 = Wm + 12288;
  const u16* Wr2 = Wm + 13312;
  const int tid = threadIdx.x;
  const int wave = tid >> 6, lane = tid & 63;
  const int fr = lane & 15, fc = lane >> 4;
  const int wrow = wave * 32;
  const int e0 = blockIdx.x * 128;
  // ================= phase A: alpha chain then radial chain (one H buffer) =
  {
    f32x4 acc[2][4];
    // alpha L1 (A from global)
    gemm16_glb<4>(elen16, e0 + wrow, lane, Wa1, acc);
    act_store16<true>(acc, ab1, ag1, abe1, u.m.H, wrow, lane);
    // alpha L2 (in-place on H)
    gemm16_lds<4>(u.m.H, wrow, lane, Wa2, acc);
    act_store16<true>(acc, ab2, ag2, abe2, u.m.H, wrow, lane);
    // alpha L3: N=4 (padded to 16); store exp(alpha) (softmax shift-free)
    gemm16_lds<1>(u.m.H, wrow, lane, Wa3, acc);
    {
      float bv = (fr < 4) ? ab3[fr] : 0.f;
      #pragma unroll
      for (int mi = 0; mi < 2; ++mi)
        #pragma unroll
        for (int j = 0; j < 4; ++j) {
          int r = wrow + mi*16 + fc*4 + j;
          float v = acc[mi][0][j] + bv;
          if (fr < 4) {
            ealpha_g[(size_t)(e0 + r)*4 + fr] = __expf(v);
            aS[r][fr] = v;
          }
        }
    }
    // radial L1 (A from global again, L2-warm; overwrites H)
    gemm16_glb<4>(elen16, e0 + wrow, lane, Wr1, acc);
    act_store16<false>(acc, tb1, nullptr, nullptr, u.m.H, wrow, lane);
    // radial L2 + sh contraction
    gemm16_lds<4>(u.m.H, wrow, lane, Wr2, acc);
    {
      float bv[4];
      #pragma unroll
      for (int ni = 0; ni < 4; ++ni) bv[ni] = tb2[ni*16 + fr];
      #pragma unroll
      for (int mi = 0; mi < 2; ++mi)
        #pragma unroll
        for (int j = 0; j < 4; ++j) {
          int r = wrow + mi*16 + fc*4 + j;
          float shv = esh[(size_t)(e0 + r)*16 + fr];
          float sc[4];
          #pragma unroll
          for (int ni = 0; ni < 4; ++ni) {
            float t = (acc[mi][ni][j] + bv[ni]) * shv;
            #pragma unroll
            for (int off = 1; off < 16; off <<= 1) t += __shfl_xor(t, off);
            sc[ni] = t;
          }
          if (fr == 0) {
            float4 sv; sv.x = sc[0]; sv.y = sc[1]; sv.z = sc[2]; sv.w = sc[3];
            *(float4*)(scal_g + (size_t)(e0 + r)*4) = sv;
            float4 cv;
            cv.x = sc[0]*aS[r][0]; cv.y = sc[1]*aS[r][1];
            cv.z = sc[2]*aS[r][2]; cv.w = sc[3]*aS[r][3];
            *(float4*)(cbuf_g + (size_t)(e0 + r)*4) = cv;
          }
        }
    }
  }
  __syncthreads();   // phase join: H reads done, Bs aliases it
  // ====== phase B: msg GEMM — wave owns 32 rows x 128 cols; A per-lane =====
  {
    const int r0 = e0 + wrow + fr;          // lane-private edge rows
    const int r1 = r0 + 16;
    const int s0 = esrc[r0], d0 = edst[r0];
    const int s1 = esrc[r1], d1 = edst[r1];
    const int sr = tid >> 1, sh = tid & 1;  // B staging: row sr, cols sh*16..+15
    const u16* bstg = Bt1 + (size_t)sr*320 + sh*16;
    // stage buf0 (k0 = 0)
    {
      const uint4* bp = (const uint4*)(bstg);
      *(uint4*)&u.g.Bs[0][sr][sh*16]     = bp[0];
      *(uint4*)&u.g.Bs[0][sr][sh*16 + 8] = bp[1];
    }
    f32x4 acc[2][8];
    #pragma unroll
    for (int mi = 0; mi < 2; ++mi)
      #pragma unroll
      for (int ni = 0; ni < 8; ++ni)
        acc[mi][ni] = (f32x4){0.f, 0.f, 0.f, 0.f};
    __syncthreads();
    #pragma unroll
    for (int k0i = 0; k0i < 10; ++k0i) {
      const int buf = k0i & 1;
      if (k0i + 1 < 10) {                   // stage next into buf^1
        const uint4* bp = (const uint4*)(bstg + (k0i + 1)*32);
        *(uint4*)&u.g.Bs[buf^1][sr][sh*16]     = bp[0];
        *(uint4*)&u.g.Bs[buf^1][sr][sh*16 + 8] = bp[1];
      }
      // A fragments: lane-private gathered rows (source uniform per k-step)
      const int k0 = k0i * 32;
      const u16 *ap0, *ap1;
      if (k0 < 128)      { ap0 = node16 + (size_t)s0*128 + k0;
                           ap1 = node16 + (size_t)s1*128 + k0; }
      else if (k0 < 256) { ap0 = node16 + (size_t)d0*128 + (k0 - 128);
                           ap1 = node16 + (size_t)d1*128 + (k0 - 128); }
      else               { ap0 = elen16 + (size_t)r0*64 + (k0 - 256);
                           ap1 = elen16 + (size_t)r1*64 + (k0 - 256); }
      f16x8 a0 = *(const f16x8*)(ap0 + fc*8);
      f16x8 a1 = *(const f16x8*)(ap1 + fc*8);
      #pragma unroll
      for (int ni = 0; ni < 8; ++ni) {
        f16x8 b = *(const f16x8*)&u.g.Bs[buf][ni*16 + fr][fc*8];
        acc[0][ni] = __builtin_amdgcn_mfma_f32_16x16x32_f16(a0, b, acc[0][ni], 0, 0, 0);
        acc[1][ni] = __builtin_amdgcn_mfma_f32_16x16x32_f16(a1, b, acc[1][ni], 0, 0, 0);
      }
      __syncthreads();
    }
    #pragma unroll
    for (int mi = 0; mi < 2; ++mi)
      #pragma unroll
      for (int j = 0; j < 4; ++j) {
        int row = wrow + mi*16 + fc*4 + j;
        size_t base = (size_t)(e0 + row)*128 + fr;
        #pragma unroll
        for (int ni = 0; ni < 8; ++ni)
          msgb[base + ni*16] = f2h(acc[mi][ni][j]);
      }
  }
}

// ---- G2S: A in regs (fp16); B plain-staged; fused s-MLP tail ---------------
__global__ __launch_bounds__(256, 4) void g2s(
    const u16* __restrict__ msgb, const u16* __restrict__ Bt2,
    const float* __restrict__ cbuf, const u16* __restrict__ Wm,
    const float* __restrict__ b1, const float* __restrict__ g1, const float* __restrict__ be1,
    const float* __restrict__ b2, const float* __restrict__ g2, const float* __restrict__ be2,
    const float* __restrict__ b3,
    float* __restrict__ oute)
{
  __shared__ u16 Bs[256][40];
  __shared__ u16 X[64][72];
  __shared__ float cS[64][4];
  const u16* Ws1 = Wm + 17408;
  const u16* Ws2 = Wm + 21504;
  const u16* Ws3 = Wm + 25600;
  const int tid = threadIdx.x, wave = tid >> 6, lane = tid & 63;
  const int e0 = blockIdx.x * 64;
  const int fr = lane & 15, fc = lane >> 4;
  const int wrow = wave * 16;
  cS[tid >> 2][tid & 3] = cbuf[(size_t)e0*4 + tid];
  f16x8 a[4];
  {
    const u16* arow = msgb + (size_t)(e0 + wrow + fr)*128 + fc*8;
    #pragma unroll
    for (int k0i = 0; k0i < 4; ++k0i) a[k0i] = *(const f16x8*)(arow + k0i*32);
  }
  f32x4 acc[16];
  #pragma unroll
  for (int ni = 0; ni < 16; ++ni) acc[ni] = (f32x4){0.f, 0.f, 0.f, 0.f};
  const u16* bsrc = Bt2 + (size_t)tid*128;
  #pragma unroll
  for (int k0i = 0; k0i < 4; ++k0i) {
    {
      const uint4* bp = (const uint4*)(bsrc + k0i*32);
      *(uint4*)&Bs[tid][0]  = bp[0];
      *(uint4*)&Bs[tid][8]  = bp[1];
      *(uint4*)&Bs[tid][16] = bp[2];
      *(uint4*)&Bs[tid][24] = bp[3];
    }
    __syncthreads();
    #pragma unroll
    for (int ni = 0; ni < 16; ++ni) {
      f16x8 b = *(const f16x8*)&Bs[ni*16 + fr][fc*8];
      acc[ni] = __builtin_amdgcn_mfma_f32_16x16x32_f16(a[k0i], b, acc[ni], 0, 0, 0);
    }
    __syncthreads();
  }
  // head-sum in-register: y0[m] = sum_h cS[row][h] * acc[4h+m]; write X fp16
  #pragma unroll
  for (int j = 0; j < 4; ++j) {
    int r = wrow + fc*4 + j;
    float c0 = cS[r][0], c1 = cS[r][1], c2 = cS[r][2], c3 = cS[r][3];
    #pragma unroll
    for (int m = 0; m < 4; ++m) {
      float y = c0*acc[m][j] + c1*acc[4+m][j] + c2*acc[8+m][j] + c3*acc[12+m][j];
      X[r][m*16 + fr] = f2h(y);
    }
  }
  // s-MLP tail: wave w owns rows [w*16, w*16+16) of X — barrier-free
  f32x4 sa[4];
  gemm16_lds1<4>(X, wrow, lane, Ws1, sa);
  act_store16_1<true>(sa, b1, g1, be1, X, wrow, lane);
  gemm16_lds1<4>(X, wrow, lane, Ws2, sa);
  act_store16_1<true>(sa, b2, g2, be2, X, wrow, lane);
  gemm16_lds1<2>(X, wrow, lane, Ws3, sa);
  {
    float bv0 = b3[fr], bv1 = b3[16 + fr];
    #pragma unroll
    for (int j = 0; j < 4; ++j) {
      int r = wrow + fc*4 + j;
      oute[(size_t)(e0 + r)*32 + fr]      = sa[0][j] + bv0;
      oute[(size_t)(e0 + r)*32 + 16 + fr] = sa[1][j] + bv1;
    }
  }
}

// ---------------- K9: per-node softmax + aggregation (no-max, exp pre-done) -
__global__ __launch_bounds__(256) void k_node(
  const int* __restrict__ offs, const int* __restrict__ eids,
  const float* __restrict__ ealpha, const float* __restrict__ scal,
  const u16* __restrict__ msgb, u16* __restrict__ nfb)
{
  const int w = threadIdx.x >> 6, lane = threadIdx.x & 63;
  const int n = blockIdx.x * 4 + w;
  const int beg = offs[n], end = offs[n+1];
  float se0=0.f, se1=0.f, se2=0.f, se3=0.f;
  float f00=0.f, f01=0.f, f10=0.f, f11=0.f, f20=0.f, f21=0.f, f30=0.f, f31=0.f;
  for (int i = beg; i < end; ++i) {
    int eid = eids[i];
    float4 a = *(const float4*)(ealpha + (size_t)eid*4);
    float4 s = *(const float4*)(scal + (size_t)eid*4);
    se0 += a.x; se1 += a.y; se2 += a.z; se3 += a.w;
    float w0 = a.x*s.x, w1 = a.y*s.y, w2 = a.z*s.z, w3 = a.w*s.w;
    float v0 = h2f(msgb[(size_t)eid*128 + lane]);
    float v1 = h2f(msgb[(size_t)eid*128 + 64 + lane]);
    f00 = fmaf(w0, v0, f00); f01 = fmaf(w0, v1, f01);
    f10 = fmaf(w1, v0, f10); f11 = fmaf(w1, v1, f11);
    f20 = fmaf(w2, v0, f20); f21 = fmaf(w2, v1, f21);
    f30 = fmaf(w3, v0, f30); f31 = fmaf(w3, v1, f31);
  }
  float i0 = 1.f/(se0 + 1e-16f), i1 = 1.f/(se1 + 1e-16f);
  float i2 = 1.f/(se2 + 1e-16f), i3 = 1.f/(se3 + 1e-16f);
  size_t b = (size_t)n * 512;
  nfb[b + 0*128 + lane]      = f2bf(f00*i0);
  nfb[b + 0*128 + 64 + lane] = f2bf(f01*i0);
  nfb[b + 1*128 + lane]      = f2bf(f10*i1);
  nfb[b + 1*128 + 64 + lane] = f2bf(f11*i1);
  nfb[b + 2*128 + lane]      = f2bf(f20*i2);
  nfb[b + 2*128 + 64 + lane] = f2bf(f21*i2);
  nfb[b + 3*128 + lane]      = f2bf(f30*i3);
  nfb[b + 3*128 + 64 + lane] = f2bf(f31*i3);
}

// ---------------- G10: node_out = node_fea @ lin_w (bf16) -------------------
__global__ __launch_bounds__(256) void g10_out(
    const u16* __restrict__ nfb, const u16* __restrict__ Bt3,
    float* __restrict__ out)
{
  __shared__ u16 As[128][40];
  __shared__ u16 Bs[128][40];
  const int tid = threadIdx.x;
  const int n0 = blockIdx.x * 128;
  const int wave = tid >> 6, lane = tid & 63;
  const int wr = (wave >> 1) * 64, wc = (wave & 1) * 64;
  const int fr = lane & 15, fc = lane >> 4;
  f32x4 acc[4][4] = {};
  const int r = tid >> 1, half = tid & 1;
  const int n = n0 + r;
  for (int k0 = 0; k0 < 512; k0 += 32) {
    uint4 z; z.x=0; z.y=0; z.z=0; z.w=0;
    uint4 v0 = z, v1 = z;
    if (n < NN) {
      const uint4* apv = (const uint4*)(nfb + (size_t)n*512 + k0 + half*16);
      v0 = apv[0]; v1 = apv[1];
    }
    *(uint4*)&As[r][half*16]     = v0;
    *(uint4*)&As[r][half*16 + 8] = v1;
    const uint4* bp = (const uint4*)(Bt3 + (size_t)r*512 + k0 + half*16);
    *(uint4*)&Bs[r][half*16]     = bp[0];
    *(uint4*)&Bs[r][half*16 + 8] = bp[1];
    __syncthreads();
    bf16x8 a[4], b[4];
    #pragma unroll
    for (int mi = 0; mi < 4; ++mi) a[mi] = *(const bf16x8*)&As[wr + mi*16 + fr][fc*8];
    #pragma unroll
    for (int ni = 0; ni < 4; ++ni) b[ni] = *(const bf16x8*)&Bs[wc + ni*16 + fr][fc*8];
    #pragma unroll
    for (int mi = 0; mi < 4; ++mi)
      #pragma unroll
      for (int ni = 0; ni < 4; ++ni)
        acc[mi][ni] = __builtin_amdgcn_mfma_f32_16x16x32_bf16(a[mi], b[ni], acc[mi][ni], 0, 0, 0);
    __syncthreads();
  }
  #pragma unroll
  for (int mi = 0; mi < 4; ++mi)
    #pragma unroll
    for (int j = 0; j < 4; ++j) {
      int rowg = n0 + wr + mi*16 + fc*4 + j;
      if (rowg < NN) {
        size_t base = (size_t)rowg*128 + wc + fr;
        #pragma unroll
        for (int ni = 0; ni < 4; ++ni)
          out[base + ni*16] = acc[mi][ni][j];
      }
    }
}

// ---------------- launch ----------------------------------------------------
extern "C" void kernel_launch(void* const* d_in, const int* in_sizes, int n_in,
                              void* d_out, int out_size, void* d_ws, size_t ws_size,
                              hipStream_t stream)
{
  const float* node_in    = (const float*)d_in[0];
  const float* edge_sh    = (const float*)d_in[2];
  const float* elen       = (const float*)d_in[3];
  const int*   esrc       = (const int*)d_in[4];
  const int*   edst       = (const int*)d_in[5];
  const float* pre_lin_w  = (const float*)d_in[7];
  const float* tp2_w1     = (const float*)d_in[8];
  const float* tp2_b1     = (const float*)d_in[9];
  const float* tp2_w2     = (const float*)d_in[10];
  const float* tp2_b2     = (const float*)d_in[11];
  const float* a_w1  = (const float*)d_in[12];
  const float* a_b1  = (const float*)d_in[13];
  const float* a_g1  = (const float*)d_in[14];
  const float* a_be1 = (const float*)d_in[15];
  const float* a_w2  = (const float*)d_in[16];
  const float* a_b2  = (const float*)d_in[17];
  const float* a_g2  = (const float*)d_in[18];
  const float* a_be2 = (const float*)d_in[19];
  const float* a_w3  = (const float*)d_in[20];
  const float* a_b3  = (const float*)d_in[21];
  const float* lin_w      = (const float*)d_in[22];
  const float* lin_edge_w = (const float*)d_in[23];
  const float* s_w1  = (const float*)d_in[24];
  const float* s_b1  = (const float*)d_in[25];
  const float* s_g1  = (const float*)d_in[26];
  const float* s_be1 = (const float*)d_in[27];
  const float* s_w2  = (const float*)d_in[28];
  const float* s_b2  = (const float*)d_in[29];
  const float* s_g2  = (const float*)d_in[30];
  const float* s_be2 = (const float*)d_in[31];
  const float* s_w3  = (const float*)d_in[32];
  const float* s_b3  = (const float*)d_in[33];

  float* out_node = (float*)d_out;
  float* out_edge = out_node + (size_t)NN * 128;

  char* ws = (char*)d_ws;
  size_t off = 0;
  auto take = [&](size_t bytes) -> char* {
    char* p = ws + off;
    off = (off + bytes + 255) & ~(size_t)255;
    return p;
  };
  u16*   msgb   = (u16*)take((size_t)EE * 128 * 2);
  u16*   elen16 = (u16*)take((size_t)EE * 64 * 2);
  u16*   node16 = (u16*)take((size_t)NN * 128 * 2);
  u16*   nfb    = (u16*)take((size_t)NN * 512 * 2);
  float* ealpha = (float*)take((size_t)EE * 4 * 4);
  float* scal   = (float*)take((size_t)EE * 4 * 4);
  float* cbuf   = (float*)take((size_t)EE * 4 * 4);
  int*   counts = (int*)take((size_t)NN * 4);
  int*   offs   = (int*)take((size_t)(NN + 1) * 4);
  int*   cursor = (int*)take((size_t)NN * 4);
  int*   eids   = (int*)take((size_t)EE * 4);
  u16*   Bt1    = (u16*)take((size_t)128 * 320 * 2);
  u16*   Bt2    = (u16*)take((size_t)256 * 128 * 2);
  u16*   Bt3    = (u16*)take((size_t)128 * 512 * 2);
  u16*   Wmlp   = (u16*)take((size_t)WTOT * 2);

  const long prep_total = (long)P3N + NN + 128*320 + 256*128 + 128*512 + WTOT;
  k_prep_all<<<(int)((prep_total + 255)/256), 256, 0, stream>>>(
      elen, node_in, elen16, node16, counts,
      pre_lin_w, lin_edge_w, lin_w, Bt1, Bt2, Bt3,
      a_w1, a_w2, a_w3, tp2_w1, tp2_w2, s_w1, s_w2, s_w3, Wmlp);
  k_count<<<EE/256, 256, 0, stream>>>(edst, counts);
  k_scan<<<1, 1024, 0, stream>>>(counts, offs, cursor);
  k_fill<<<EE/256, 256, 0, stream>>>(edst, cursor, eids);
  k_sort2<<<NN/4, 256, 0, stream>>>(offs, eids);
  k_edge1<<<EE/128, 256, 0, stream>>>(elen16, edge_sh, Wmlp,
                                      a_b1, a_g1, a_be1, a_b2, a_g2, a_be2, a_b3,
                                      tp2_b1, tp2_b2, ealpha, scal, cbuf,
                                      node16, esrc, edst, Bt1, msgb);
  g2s<<<EE/64, 256, 0, stream>>>(msgb, Bt2, cbuf, Wmlp,
                                 s_b1, s_g1, s_be1, s_b2, s_g2, s_be2, s_b3, out_edge);
  k_node<<<NN/4, 256, 0, stream>>>(offs, eids, ealpha, scal, msgb, nfb);
  g10_out<<<(NN + 127)/128, 256, 0, stream>>>(nfb, Bt3, out_node);
}